// Round 3
// baseline (234.910 us; speedup 1.0000x reference)
//
#include <hip/hip_runtime.h>
#include <stdint.h>

#define N_VOX 262144
#define CCH 64
#define KOFF 27

typedef short v8s __attribute__((ext_vector_type(8)));
typedef float v4f __attribute__((ext_vector_type(4)));
typedef int   v4i __attribute__((ext_vector_type(4)));

__device__ __forceinline__ unsigned short f2bf(float f) {
  unsigned u = __float_as_uint(f);
  u += 0x7fff + ((u >> 16) & 1);   // RNE
  return (unsigned short)(u >> 16);
}

// --- deterministic sniff of the mask buffer's dtype (byte-bool vs 32-bit) ---
__global__ void prep_flag_k(const unsigned* __restrict__ m, int* __restrict__ flag) {
  if (threadIdx.x == 0) {
    int wordlike = 1;  // int32 0/1 or float32 0.0/1.0
    for (int i = 0; i < 256; ++i) {
      unsigned v = m[i];
      if (v > 1u && v != 0x3f800000u) { wordlike = 0; break; }
    }
    *flag = wordlike ? 0 : 2;   // 0: read as u32 words, 2: read as bytes
  }
}

__global__ void prep_mask_k(const void* __restrict__ m, const int* __restrict__ flag,
                            unsigned char* __restrict__ mb, int n) {
  int f = *flag;
  for (int i = blockIdx.x * blockDim.x + threadIdx.x; i < n; i += gridDim.x * blockDim.x) {
    unsigned char v;
    if (f == 2) v = (((const unsigned char*)m)[i] != 0);
    else        v = (((const unsigned*)m)[i] != 0u);
    mb[i] = v;
  }
}

// --- features fp32 -> bf16 table (halves gather traffic, frags load direct) ---
__global__ void prep_feat_k(const float* __restrict__ src, unsigned short* __restrict__ dst, int n8) {
  int i = blockIdx.x * blockDim.x + threadIdx.x;
  if (i >= n8) return;
  const float4* s4 = (const float4*)src;
  float4 a = s4[i * 2], b = s4[i * 2 + 1];
  v8s v;
  v[0] = (short)f2bf(a.x); v[1] = (short)f2bf(a.y);
  v[2] = (short)f2bf(a.z); v[3] = (short)f2bf(a.w);
  v[4] = (short)f2bf(b.x); v[5] = (short)f2bf(b.y);
  v[6] = (short)f2bf(b.z); v[7] = (short)f2bf(b.w);
  ((v8s*)dst)[i] = v;
}

// --- W [27][cin][cout] fp32 -> Wt bf16 [27][cout][cin], XOR-swizzled for LDS ---
__global__ void prep_w_k(const float* __restrict__ w, unsigned short* __restrict__ wt) {
  int i = blockIdx.x * blockDim.x + threadIdx.x;
  if (i >= KOFF * CCH * CCH) return;
  int k = i >> 12, rem = i & 4095, kk = rem >> 6, col = rem & 63;
  wt[(k << 12) + (col << 6) + (kk ^ ((col & 7) << 3))] = f2bf(w[i]);
}

// raw barrier: ds ops drained (dbuf safety) but VMEM gathers STAY IN FLIGHT
// (__syncthreads would emit s_waitcnt vmcnt(0) and serialize gather latency)
__device__ __forceinline__ void barrier_keep_vmem() {
  asm volatile("s_waitcnt lgkmcnt(0)" ::: "memory");
  __builtin_amdgcn_s_barrier();
  __builtin_amdgcn_sched_barrier(0);
}

// --- one sparse-conv layer, pipelined with vmem-preserving barriers ---
// 128 rows/block (4 waves x 32). Gathers 2 offsets ahead, idx/mask 4 ahead,
// W 1 ahead (LDS double-buffer). LAYER==1: bf16 h. LAYER==2: f32 + residual.
template <int LAYER>
__global__ __launch_bounds__(256, 3)
void conv_layer_k(const v8s* __restrict__ src, const int* __restrict__ nbr,
                  const unsigned char* __restrict__ mb,
                  const v4i* __restrict__ wt, const float* __restrict__ bias,
                  const float* __restrict__ resid, void* __restrict__ outp) {
  __shared__ v4i ldsB[2][512];   // double-buffered Wt_k: 2 x 8 KiB
  const int tid = threadIdx.x;
  const int lane = tid & 63;
  const int wv = tid >> 6;
  const int l15 = lane & 15;
  const int g = lane >> 4;
  const int rowbase = blockIdx.x * 128 + wv * 32;
  const int r0 = rowbase + l15;
  const int r1 = rowbase + 16 + l15;

  // ---- prologue ----
  v4i w0a = wt[tid], w0b = wt[256 + tid];           // W(0)

  // idx/mask for k = 0..3
  int i0_0 = nbr[r0],             i0_1 = nbr[r1];
  int i1_0 = nbr[N_VOX + r0],     i1_1 = nbr[N_VOX + r1];
  int i2_0 = nbr[2 * N_VOX + r0], i2_1 = nbr[2 * N_VOX + r1];
  int i3_0 = nbr[3 * N_VOX + r0], i3_1 = nbr[3 * N_VOX + r1];
  bool m0_0 = mb[r0],             m0_1 = mb[r1];
  bool m1_0 = mb[N_VOX + r0],     m1_1 = mb[N_VOX + r1];
  bool m2_0 = mb[2 * N_VOX + r0], m2_1 = mb[2 * N_VOX + r1];
  bool m3_0 = mb[3 * N_VOX + r0], m3_1 = mb[3 * N_VOX + r1];

  // gathers for k=0 (cur) and k=1 (n1)
  v8s a0c = {}, a1c = {}, a2c = {}, a3c = {};
  if (m0_0) { a0c = src[i0_0 * 8 + g]; a1c = src[i0_0 * 8 + 4 + g]; }
  if (m0_1) { a2c = src[i0_1 * 8 + g]; a3c = src[i0_1 * 8 + 4 + g]; }
  v8s a0n = {}, a1n = {}, a2n = {}, a3n = {};
  if (m1_0) { a0n = src[i1_0 * 8 + g]; a1n = src[i1_0 * 8 + 4 + g]; }
  if (m1_1) { a2n = src[i1_1 * 8 + g]; a3n = src[i1_1 * 8 + 4 + g]; }

  ldsB[0][tid] = w0a;
  ldsB[0][256 + tid] = w0b;
  barrier_keep_vmem();

  v4f acc0[4] = {}, acc1[4] = {};
  int cur = 0;

  for (int k = 0; k < KOFF; ++k) {
    const int kc1 = (k + 1 < KOFF) ? k + 1 : KOFF - 1;
    const int kc4 = (k + 4 < KOFF) ? k + 4 : KOFF - 1;

    // gathers for k+2 (idx/mask loaded 2 iterations ago; extra loads on the
    // last 2 iterations hit clamped-valid addresses and are never consumed)
    v8s a0f = {}, a1f = {}, a2f = {}, a3f = {};
    if (m2_0) { a0f = src[i2_0 * 8 + g]; a1f = src[i2_0 * 8 + 4 + g]; }
    if (m2_1) { a2f = src[i2_1 * 8 + g]; a3f = src[i2_1 * 8 + 4 + g]; }

    // W(k+1) prefetch
    v4i nw0 = wt[kc1 * 512 + tid];
    v4i nw1 = wt[kc1 * 512 + 256 + tid];

    // idx/mask (k+4) prefetch
    int t0 = nbr[kc4 * N_VOX + r0], t1 = nbr[kc4 * N_VOX + r1];
    bool u0 = mb[kc4 * N_VOX + r0], u1 = mb[kc4 * N_VOX + r1];

    // B fragments for k from LDS (swizzled -> conflict-free b128 reads)
    const short* Bs = (const short*)ldsB[cur];
    v8s bf0[4], bf1[4];
#pragma unroll
    for (int ct = 0; ct < 4; ++ct) {
      int col = ct * 16 + l15;
      int sw = (col & 7) << 3;
      int base = col << 6;
      bf0[ct] = *(const v8s*)(Bs + base + ((g * 8) ^ sw));
      bf1[ct] = *(const v8s*)(Bs + base + ((32 + g * 8) ^ sw));
    }

#pragma unroll
    for (int ct = 0; ct < 4; ++ct) {
      acc0[ct] = __builtin_amdgcn_mfma_f32_16x16x32_bf16(a0c, bf0[ct], acc0[ct], 0, 0, 0);
      acc0[ct] = __builtin_amdgcn_mfma_f32_16x16x32_bf16(a1c, bf1[ct], acc0[ct], 0, 0, 0);
      acc1[ct] = __builtin_amdgcn_mfma_f32_16x16x32_bf16(a2c, bf0[ct], acc1[ct], 0, 0, 0);
      acc1[ct] = __builtin_amdgcn_mfma_f32_16x16x32_bf16(a3c, bf1[ct], acc1[ct], 0, 0, 0);
    }

    // stage B(k+1) into the other buffer (vmem gathers stay in flight)
    ldsB[cur ^ 1][tid] = nw0;
    ldsB[cur ^ 1][256 + tid] = nw1;
    barrier_keep_vmem();
    cur ^= 1;

    // rotate pipeline registers (all static names, no runtime indexing)
    a0c = a0n; a1c = a1n; a2c = a2n; a3c = a3n;
    a0n = a0f; a1n = a1f; a2n = a2f; a3n = a3f;
    i2_0 = i3_0; i2_1 = i3_1; m2_0 = m3_0; m2_1 = m3_1;
    i3_0 = t0;   i3_1 = t1;   m3_0 = u0;   m3_1 = u1;
  }

  float bv[4];
#pragma unroll
  for (int ct = 0; ct < 4; ++ct) bv[ct] = bias[ct * 16 + l15];

#pragma unroll
  for (int rt = 0; rt < 2; ++rt) {
    int row0 = rowbase + rt * 16 + g * 4;   // D row = (lane>>4)*4 + i
#pragma unroll
    for (int ct = 0; ct < 4; ++ct) {
      int col = ct * 16 + l15;              // D col = lane & 15
      const v4f& a = rt ? acc1[ct] : acc0[ct];
#pragma unroll
      for (int i = 0; i < 4; ++i) {
        float v = a[i] + bv[ct];
        int o = (row0 + i) * CCH + col;
        if (LAYER == 1) ((unsigned short*)outp)[o] = f2bf(v);
        else            ((float*)outp)[o] = v + resid[o];
      }
    }
  }
}

extern "C" void kernel_launch(void* const* d_in, const int* in_sizes, int n_in,
                              void* d_out, int out_size, void* d_ws, size_t ws_size,
                              hipStream_t stream) {
  const float* feat = (const float*)d_in[0];
  const int* nbr    = (const int*)d_in[1];
  const void* mask  = d_in[2];
  const float* w1   = (const float*)d_in[3];
  const float* b1   = (const float*)d_in[4];
  const float* w2   = (const float*)d_in[5];
  const float* b2   = (const float*)d_in[6];

  char* ws = (char*)d_ws;
  unsigned short* featb = (unsigned short*)ws;                    // 33,554,432 B
  unsigned short* hb    = (unsigned short*)(ws + 33554432);       // 33,554,432 B
  unsigned char*  maskb = (unsigned char*)(ws + 67108864);        //  7,077,888 B
  unsigned short* wt1   = (unsigned short*)(ws + 74186752);       //    221,184 B
  unsigned short* wt2   = (unsigned short*)(ws + 74407936);       //    221,184 B
  int*            flag  = (int*)(ws + 74629120);

  prep_flag_k<<<1, 64, 0, stream>>>((const unsigned*)mask, flag);
  prep_mask_k<<<4096, 256, 0, stream>>>(mask, flag, maskb, KOFF * N_VOX);
  prep_feat_k<<<8192, 256, 0, stream>>>(feat, featb, N_VOX * CCH / 8);
  prep_w_k<<<432, 256, 0, stream>>>(w1, wt1);
  prep_w_k<<<432, 256, 0, stream>>>(w2, wt2);

  conv_layer_k<1><<<2048, 256, 0, stream>>>((const v8s*)featb, nbr, maskb,
                                            (const v4i*)wt1, b1, nullptr, (void*)hb);
  conv_layer_k<2><<<2048, 256, 0, stream>>>((const v8s*)hb, nbr, maskb,
                                            (const v4i*)wt2, b2, feat, (void*)d_out);
}